// Round 1
// baseline (1577.963 us; speedup 1.0000x reference)
//
#include <hip/hip_runtime.h>
#include <math.h>

#define VOCAB 64
#define H 64
#define BB 256
#define LL 2048

// 64-lane wave sum via DPP (row_shr 1/2/4/8, row_bcast15, row_bcast31), then
// broadcast total from lane 63. All VALU-pipe: ~6x8 cycles, no LDS latency.
__device__ __forceinline__ float wave_sum_dpp(float x) {
  int t;
  float r = x;
  t = __builtin_amdgcn_update_dpp(0, __float_as_int(r), 0x111, 0xf, 0xf, true); r += __int_as_float(t);
  t = __builtin_amdgcn_update_dpp(0, __float_as_int(r), 0x112, 0xf, 0xf, true); r += __int_as_float(t);
  t = __builtin_amdgcn_update_dpp(0, __float_as_int(r), 0x114, 0xf, 0xf, true); r += __int_as_float(t);
  t = __builtin_amdgcn_update_dpp(0, __float_as_int(r), 0x118, 0xf, 0xf, true); r += __int_as_float(t);
  t = __builtin_amdgcn_update_dpp(0, __float_as_int(r), 0x142, 0xf, 0xf, true); r += __int_as_float(t);
  t = __builtin_amdgcn_update_dpp(0, __float_as_int(r), 0x143, 0xf, 0xf, true); r += __int_as_float(t);
  return __int_as_float(__builtin_amdgcn_readlane(__float_as_int(r), 63));
}

// Phase 1: hidden depends only on the token id -> precompute 64 hidden vectors.
// grid = VOCAB blocks, block = 64 threads (1 wave). Block c computes table[c][:].
__global__ void encode_kernel(const float* __restrict__ embed, const float* __restrict__ W1,
                              const float* __restrict__ b1, const float* __restrict__ W2,
                              const float* __restrict__ b2, const float* __restrict__ gamma,
                              const float* __restrict__ beta, float* __restrict__ table,
                              float* __restrict__ kkg) {
  const int c = blockIdx.x;
  const int j = threadIdx.x;
  __shared__ float hs[H];
  __shared__ float zs[2 * H];
  const float h = embed[c * H + j];
  hs[j] = h;
  __syncthreads();
  float z0 = b1[j], z1 = b1[j + H];
#pragma unroll 8
  for (int i = 0; i < H; ++i) {
    const float hi = hs[i];
    z0 = fmaf(hi, W1[i * 2 * H + j], z0);
    z1 = fmaf(hi, W1[i * 2 * H + j + H], z1);
  }
  z0 = fmaxf(z0, 0.f);
  z1 = fmaxf(z1, 0.f);
  zs[j] = z0;
  zs[j + H] = z1;
  __syncthreads();
  float ff = b2[j];
#pragma unroll 8
  for (int m = 0; m < 2 * H; ++m) ff = fmaf(zs[m], W2[m * H + j], ff);
  const float x = h + ff;
  const float mu = wave_sum_dpp(x) * (1.f / 64.f);
  const float d = x - mu;
  const float var = wave_sum_dpp(d * d) * (1.f / 64.f);
  const float y = d * (1.f / sqrtf(var + 1e-5f)) * gamma[j] + beta[j];
  table[c * H + j] = y;
  const float s2 = wave_sum_dpp(y * y);
  if (j == 0) kkg[c] = s2;
}

// Phase 2+3: per-batch sequential scan. One block = one wave = one batch.
// Lane i owns row M[i][:] in 64 VGPRs. Gate via analytic norm delta:
// ||M+dM||^2 - ||M||^2 = 2*(dv.v_pred) + (dv.dv)*(k.k)  -> one wave reduction.
__global__ void scan_kernel(const int* __restrict__ seq, const float* __restrict__ table,
                            const float* __restrict__ kkg, const float* __restrict__ Wr,
                            const float* __restrict__ br, const float* __restrict__ Wo,
                            const float* __restrict__ bo, float* __restrict__ out,
                            float* __restrict__ counts) {
  const int b = blockIdx.x;
  const int lane = threadIdx.x;
  __shared__ float T[H * VOCAB];   // 16 KB: table, row c = key vector for token c
  __shared__ float KK[VOCAB];
  __shared__ int toks[LL];         // 8 KB: this batch's token stream
  __shared__ float xv[H];

  {
    const float4* src = (const float4*)table;
    float4* dst = (float4*)T;
#pragma unroll
    for (int q = 0; q < 16; ++q) dst[q * 64 + lane] = src[q * 64 + lane];
    KK[lane] = kkg[lane];
    const int4* ssrc = (const int4*)(seq + (long)b * LL);
    int4* sdst = (int4*)toks;
#pragma unroll
    for (int q = 0; q < 8; ++q) sdst[q * 64 + lane] = ssrc[q * 64 + lane];
  }
  __syncthreads();

  float M[H];
#pragma unroll
  for (int j = 0; j < H; ++j) M[j] = 0.f;
  float wcount = 0.f;

  int c = toks[0];
  for (int t = 0; t < LL - 1; ++t) {
    const int cnext = toks[t + 1];  // prefetch next token (hides LDS latency)
    const float4* kp = (const float4*)(T + c * H);
    float kv[H];
    float vp0 = 0.f, vp1 = 0.f, vp2 = 0.f, vp3 = 0.f;
#pragma unroll
    for (int q = 0; q < 16; ++q) {
      const float4 k4 = kp[q];  // broadcast read, conflict-free
      kv[4 * q + 0] = k4.x; kv[4 * q + 1] = k4.y;
      kv[4 * q + 2] = k4.z; kv[4 * q + 3] = k4.w;
      vp0 = fmaf(M[4 * q + 0], k4.x, vp0);
      vp1 = fmaf(M[4 * q + 1], k4.y, vp1);
      vp2 = fmaf(M[4 * q + 2], k4.z, vp2);
      vp3 = fmaf(M[4 * q + 3], k4.w, vp3);
    }
    const float vp = (vp0 + vp1) + (vp2 + vp3);
    const float kk = KK[c];
    const float ki = T[c * H + lane];        // k[lane], conflict-free
    const float dv = ki - vp / (kk + 1e-6f); // true divide to track reference
    const float a = dv * (2.f * vp + dv * kk);
    const float s = wave_sum_dpp(a);         // uniform
    if (s > 0.f) {                           // wave-uniform branch
#pragma unroll
      for (int j = 0; j < H; ++j) M[j] = fmaf(dv, kv[j], M[j]);
      wcount += 1.f;
    }
    c = cnext;
  }

  // epilogue: ctx = M @ table[c_last]  (c now holds toks[LL-1])
  {
    const float4* kp = (const float4*)(T + c * H);
    float c0 = 0.f, c1 = 0.f, c2 = 0.f, c3 = 0.f;
#pragma unroll
    for (int q = 0; q < 16; ++q) {
      const float4 k4 = kp[q];
      c0 = fmaf(M[4 * q + 0], k4.x, c0);
      c1 = fmaf(M[4 * q + 1], k4.y, c1);
      c2 = fmaf(M[4 * q + 2], k4.z, c2);
      c3 = fmaf(M[4 * q + 3], k4.w, c3);
    }
    xv[lane] = (c0 + c1) + (c2 + c3);
  }
  __syncthreads();
  float t1 = br[lane];
#pragma unroll 8
  for (int i = 0; i < H; ++i) t1 = fmaf(xv[i], Wr[i * H + lane], t1);
  __syncthreads();
  xv[lane] = t1;
  __syncthreads();
  float lg = bo[lane];
#pragma unroll 8
  for (int m = 0; m < H; ++m) lg = fmaf(xv[m], Wo[m * H + lane], lg);
  out[(long)b * H + lane] = lg;
  if (lane == 0) counts[b] = wcount;
}

__global__ void finalize_kernel(const float* __restrict__ counts, float* __restrict__ out) {
  const int lane = threadIdx.x;  // 256 threads
  __shared__ float sbuf[BB];
  sbuf[lane] = counts[lane];
  __syncthreads();
  for (int off = BB / 2; off > 0; off >>= 1) {
    if (lane < off) sbuf[lane] += sbuf[lane + off];
    __syncthreads();
  }
  if (lane == 0) out[BB * H] = sbuf[0] / (float)(BB * (LL - 1));
}

extern "C" void kernel_launch(void* const* d_in, const int* in_sizes, int n_in,
                              void* d_out, int out_size, void* d_ws, size_t ws_size,
                              hipStream_t stream) {
  const int* seq      = (const int*)d_in[0];
  const float* embed  = (const float*)d_in[1];
  const float* W1     = (const float*)d_in[2];
  const float* b1     = (const float*)d_in[3];
  const float* W2     = (const float*)d_in[4];
  const float* b2     = (const float*)d_in[5];
  const float* gamma  = (const float*)d_in[6];
  const float* beta   = (const float*)d_in[7];
  const float* Wr     = (const float*)d_in[8];
  const float* br     = (const float*)d_in[9];
  const float* Wo     = (const float*)d_in[10];
  const float* bo     = (const float*)d_in[11];
  float* out = (float*)d_out;

  float* table  = (float*)d_ws;          // 64*64 f32
  float* kkg    = table + VOCAB * H;     // 64 f32
  float* counts = kkg + VOCAB;           // 256 f32

  encode_kernel<<<VOCAB, H, 0, stream>>>(embed, W1, b1, W2, b2, gamma, beta, table, kkg);
  scan_kernel<<<BB, H, 0, stream>>>(seq, table, kkg, Wr, br, Wo, bo, out, counts);
  finalize_kernel<<<1, BB, 0, stream>>>(counts, out);
}

// Round 2
// 809.236 us; speedup vs baseline: 1.9499x; 1.9499x over previous
//
#include <hip/hip_runtime.h>
#include <math.h>

#define VOCAB 64
#define H 64
#define BB 256
#define LL 2048

// 64-lane wave sum via DPP (row_shr 1/2/4/8, row_bcast15, row_bcast31), then
// broadcast total from lane 63. All VALU-pipe, no LDS latency.
__device__ __forceinline__ float wave_sum_dpp(float x) {
  int t;
  float r = x;
  t = __builtin_amdgcn_update_dpp(0, __float_as_int(r), 0x111, 0xf, 0xf, true); r += __int_as_float(t);
  t = __builtin_amdgcn_update_dpp(0, __float_as_int(r), 0x112, 0xf, 0xf, true); r += __int_as_float(t);
  t = __builtin_amdgcn_update_dpp(0, __float_as_int(r), 0x114, 0xf, 0xf, true); r += __int_as_float(t);
  t = __builtin_amdgcn_update_dpp(0, __float_as_int(r), 0x118, 0xf, 0xf, true); r += __int_as_float(t);
  t = __builtin_amdgcn_update_dpp(0, __float_as_int(r), 0x142, 0xf, 0xf, true); r += __int_as_float(t);
  t = __builtin_amdgcn_update_dpp(0, __float_as_int(r), 0x143, 0xf, 0xf, true); r += __int_as_float(t);
  return __int_as_float(__builtin_amdgcn_readlane(__float_as_int(r), 63));
}

// Phase 1: hidden depends only on the token id -> precompute 64 hidden vectors.
__global__ __launch_bounds__(64, 1) void encode_kernel(
    const float* __restrict__ embed, const float* __restrict__ W1,
    const float* __restrict__ b1, const float* __restrict__ W2,
    const float* __restrict__ b2, const float* __restrict__ gamma,
    const float* __restrict__ beta, float* __restrict__ table,
    float* __restrict__ kkg) {
  const int c = blockIdx.x;
  const int j = threadIdx.x;
  __shared__ float hs[H];
  __shared__ float zs[2 * H];
  const float h = embed[c * H + j];
  hs[j] = h;
  __syncthreads();
  float z0 = b1[j], z1 = b1[j + H];
#pragma unroll 8
  for (int i = 0; i < H; ++i) {
    const float hi = hs[i];
    z0 = fmaf(hi, W1[i * 2 * H + j], z0);
    z1 = fmaf(hi, W1[i * 2 * H + j + H], z1);
  }
  z0 = fmaxf(z0, 0.f);
  z1 = fmaxf(z1, 0.f);
  zs[j] = z0;
  zs[j + H] = z1;
  __syncthreads();
  float ff = b2[j];
#pragma unroll 8
  for (int m = 0; m < 2 * H; ++m) ff = fmaf(zs[m], W2[m * H + j], ff);
  const float x = h + ff;
  const float mu = wave_sum_dpp(x) * (1.f / 64.f);
  const float d = x - mu;
  const float var = wave_sum_dpp(d * d) * (1.f / 64.f);
  const float y = d * (1.f / sqrtf(var + 1e-5f)) * gamma[j] + beta[j];
  table[c * H + j] = y;
  const float s2 = wave_sum_dpp(y * y);
  if (j == 0) kkg[c] = s2;
}

// Phase 2+3: per-batch sequential scan. One block = one wave = one batch.
// Lane i owns row M[i][:] in VGPRs (launch_bounds(64,1) -> up to 512 VGPRs,
// no spill). Gate via analytic norm delta, one DPP wave-reduction per step.
__global__ __launch_bounds__(64, 1) void scan_kernel(
    const int* __restrict__ seq, const float* __restrict__ table,
    const float* __restrict__ kkg, const float* __restrict__ Wr,
    const float* __restrict__ br, const float* __restrict__ Wo,
    const float* __restrict__ bo, float* __restrict__ out,
    float* __restrict__ counts) {
  const int b = blockIdx.x;
  const int lane = threadIdx.x;
  __shared__ float T[H * VOCAB];   // 16 KB: table, row c = key vector for token c
  __shared__ float KK[VOCAB];
  __shared__ int toks[LL];         // 8 KB: this batch's token stream
  __shared__ float xv[H];

  {
    const float4* src = (const float4*)table;
    float4* dst = (float4*)T;
#pragma unroll
    for (int q = 0; q < 16; ++q) dst[q * 64 + lane] = src[q * 64 + lane];
    KK[lane] = kkg[lane];
    const int4* ssrc = (const int4*)(seq + (long)b * LL);
    int4* sdst = (int4*)toks;
#pragma unroll
    for (int q = 0; q < 8; ++q) sdst[q * 64 + lane] = ssrc[q * 64 + lane];
  }
  __syncthreads();

  float M[H];
#pragma unroll
  for (int j = 0; j < H; ++j) M[j] = 0.f;
  float wcount = 0.f;

  int c = toks[0];
  for (int t = 0; t < LL - 1; ++t) {
    const int cnext = toks[t + 1];  // prefetch next token (hides LDS latency)
    const float4* kp = (const float4*)(T + c * H);
    float kv[H];
    float vp0 = 0.f, vp1 = 0.f, vp2 = 0.f, vp3 = 0.f;
#pragma unroll
    for (int q = 0; q < 16; ++q) {
      const float4 k4 = kp[q];  // broadcast read, conflict-free
      kv[4 * q + 0] = k4.x; kv[4 * q + 1] = k4.y;
      kv[4 * q + 2] = k4.z; kv[4 * q + 3] = k4.w;
      vp0 = fmaf(M[4 * q + 0], k4.x, vp0);
      vp1 = fmaf(M[4 * q + 1], k4.y, vp1);
      vp2 = fmaf(M[4 * q + 2], k4.z, vp2);
      vp3 = fmaf(M[4 * q + 3], k4.w, vp3);
    }
    const float vp = (vp0 + vp1) + (vp2 + vp3);
    const float kk = KK[c];
    const float ki = T[c * H + lane];        // k[lane], conflict-free
    const float dv = ki - vp / (kk + 1e-6f); // true divide to track reference
    const float a = dv * (2.f * vp + dv * kk);
    const float s = wave_sum_dpp(a);         // uniform
    if (s > 0.f) {                           // wave-uniform branch
#pragma unroll
      for (int j = 0; j < H; ++j) M[j] = fmaf(dv, kv[j], M[j]);
      wcount += 1.f;
    }
    c = cnext;
  }

  // epilogue: ctx = M @ table[c_last]  (c now holds toks[LL-1])
  {
    const float4* kp = (const float4*)(T + c * H);
    float c0 = 0.f, c1 = 0.f, c2 = 0.f, c3 = 0.f;
#pragma unroll
    for (int q = 0; q < 16; ++q) {
      const float4 k4 = kp[q];
      c0 = fmaf(M[4 * q + 0], k4.x, c0);
      c1 = fmaf(M[4 * q + 1], k4.y, c1);
      c2 = fmaf(M[4 * q + 2], k4.z, c2);
      c3 = fmaf(M[4 * q + 3], k4.w, c3);
    }
    xv[lane] = (c0 + c1) + (c2 + c3);
  }
  __syncthreads();
  float t1 = br[lane];
#pragma unroll 8
  for (int i = 0; i < H; ++i) t1 = fmaf(xv[i], Wr[i * H + lane], t1);
  __syncthreads();
  xv[lane] = t1;
  __syncthreads();
  float lg = bo[lane];
#pragma unroll 8
  for (int m = 0; m < H; ++m) lg = fmaf(xv[m], Wo[m * H + lane], lg);
  out[(long)b * H + lane] = lg;
  if (lane == 0) counts[b] = wcount;
}

__global__ __launch_bounds__(256, 1) void finalize_kernel(const float* __restrict__ counts,
                                                          float* __restrict__ out) {
  const int lane = threadIdx.x;  // 256 threads
  __shared__ float sbuf[BB];
  sbuf[lane] = counts[lane];
  __syncthreads();
  for (int off = BB / 2; off > 0; off >>= 1) {
    if (lane < off) sbuf[lane] += sbuf[lane + off];
    __syncthreads();
  }
  if (lane == 0) out[BB * H] = sbuf[0] / (float)(BB * (LL - 1));
}

extern "C" void kernel_launch(void* const* d_in, const int* in_sizes, int n_in,
                              void* d_out, int out_size, void* d_ws, size_t ws_size,
                              hipStream_t stream) {
  const int* seq      = (const int*)d_in[0];
  const float* embed  = (const float*)d_in[1];
  const float* W1     = (const float*)d_in[2];
  const float* b1     = (const float*)d_in[3];
  const float* W2     = (const float*)d_in[4];
  const float* b2     = (const float*)d_in[5];
  const float* gamma  = (const float*)d_in[6];
  const float* beta   = (const float*)d_in[7];
  const float* Wr     = (const float*)d_in[8];
  const float* br     = (const float*)d_in[9];
  const float* Wo     = (const float*)d_in[10];
  const float* bo     = (const float*)d_in[11];
  float* out = (float*)d_out;

  float* table  = (float*)d_ws;          // 64*64 f32
  float* kkg    = table + VOCAB * H;     // 64 f32
  float* counts = kkg + VOCAB;           // 256 f32

  encode_kernel<<<VOCAB, H, 0, stream>>>(embed, W1, b1, W2, b2, gamma, beta, table, kkg);
  scan_kernel<<<BB, H, 0, stream>>>(seq, table, kkg, Wr, br, Wo, bo, out, counts);
  finalize_kernel<<<1, BB, 0, stream>>>(counts, out);
}

// Round 3
// 724.845 us; speedup vs baseline: 2.1770x; 1.1164x over previous
//
#include <hip/hip_runtime.h>
#include <math.h>

#define VOCAB 64
#define H 64
#define BB 256
#define LL 2048

typedef float v2f __attribute__((ext_vector_type(2)));

// 64-lane wave sum via DPP (row_shr 1/2/4/8, row_bcast15, row_bcast31), then
// broadcast total from lane 63. All VALU-pipe, no LDS latency.
__device__ __forceinline__ float wave_sum_dpp(float x) {
  int t;
  float r = x;
  t = __builtin_amdgcn_update_dpp(0, __float_as_int(r), 0x111, 0xf, 0xf, true); r += __int_as_float(t);
  t = __builtin_amdgcn_update_dpp(0, __float_as_int(r), 0x112, 0xf, 0xf, true); r += __int_as_float(t);
  t = __builtin_amdgcn_update_dpp(0, __float_as_int(r), 0x114, 0xf, 0xf, true); r += __int_as_float(t);
  t = __builtin_amdgcn_update_dpp(0, __float_as_int(r), 0x118, 0xf, 0xf, true); r += __int_as_float(t);
  t = __builtin_amdgcn_update_dpp(0, __float_as_int(r), 0x142, 0xf, 0xf, true); r += __int_as_float(t);
  t = __builtin_amdgcn_update_dpp(0, __float_as_int(r), 0x143, 0xf, 0xf, true); r += __int_as_float(t);
  return __int_as_float(__builtin_amdgcn_readlane(__float_as_int(r), 63));
}

// Phase 1: hidden depends only on the token id -> precompute 64 hidden vectors.
__global__ __launch_bounds__(64, 1) void encode_kernel(
    const float* __restrict__ embed, const float* __restrict__ W1,
    const float* __restrict__ b1, const float* __restrict__ W2,
    const float* __restrict__ b2, const float* __restrict__ gamma,
    const float* __restrict__ beta, float* __restrict__ table,
    float* __restrict__ kkg) {
  const int c = blockIdx.x;
  const int j = threadIdx.x;
  __shared__ float hs[H];
  __shared__ float zs[2 * H];
  const float h = embed[c * H + j];
  hs[j] = h;
  __syncthreads();
  float z0 = b1[j], z1 = b1[j + H];
#pragma unroll 8
  for (int i = 0; i < H; ++i) {
    const float hi = hs[i];
    z0 = fmaf(hi, W1[i * 2 * H + j], z0);
    z1 = fmaf(hi, W1[i * 2 * H + j + H], z1);
  }
  z0 = fmaxf(z0, 0.f);
  z1 = fmaxf(z1, 0.f);
  zs[j] = z0;
  zs[j + H] = z1;
  __syncthreads();
  float ff = b2[j];
#pragma unroll 8
  for (int m = 0; m < 2 * H; ++m) ff = fmaf(zs[m], W2[m * H + j], ff);
  const float x = h + ff;
  const float mu = wave_sum_dpp(x) * (1.f / 64.f);
  const float d = x - mu;
  const float var = wave_sum_dpp(d * d) * (1.f / 64.f);
  const float y = d * (1.f / sqrtf(var + 1e-5f)) * gamma[j] + beta[j];
  table[c * H + j] = y;
  const float s2 = wave_sum_dpp(y * y);
  if (j == 0) kkg[c] = s2;
}

// Phase 2+3: per-batch sequential scan. One block = one wave = one batch.
// Lane i owns row M[i][:] as 32 float2 (v_pk_fma_f32-capable). Branchless
// gate; update(t) fused with dot(t+1) so the whole step is one straight-line
// region. Arithmetic order identical to the round-2 kernel (bit-exact).
__global__ __launch_bounds__(64, 1) void scan_kernel(
    const int* __restrict__ seq, const float* __restrict__ table,
    const float* __restrict__ kkg, const float* __restrict__ Wr,
    const float* __restrict__ br, const float* __restrict__ Wo,
    const float* __restrict__ bo, float* __restrict__ out,
    float* __restrict__ counts) {
  const int b = blockIdx.x;
  const int lane = threadIdx.x;
  __shared__ float T[H * VOCAB];   // 16 KB: table, row c = key vector for token c
  __shared__ float KK[VOCAB];
  __shared__ int toks[LL];         // 8 KB: this batch's token stream
  __shared__ float xv[H];

  {
    const float4* src = (const float4*)table;
    float4* dst = (float4*)T;
#pragma unroll
    for (int q = 0; q < 16; ++q) dst[q * 64 + lane] = src[q * 64 + lane];
    KK[lane] = kkg[lane];
    const int4* ssrc = (const int4*)(seq + (long)b * LL);
    int4* sdst = (int4*)toks;
#pragma unroll
    for (int q = 0; q < 8; ++q) sdst[q * 64 + lane] = ssrc[q * 64 + lane];
  }
  __syncthreads();

  v2f M2[32];
#pragma unroll
  for (int r = 0; r < 32; ++r) M2[r] = (v2f){0.f, 0.f};
  float wcount = 0.f;

  int c = toks[0];
  float sc = T[c * H + lane];  // k_t[lane]
  float kk = KK[c];
  // vp accumulators for the CURRENT step: (vpA.x+vpA.y)+(vpB.x+vpB.y).
  // Step 0: M = 0 -> vp = 0.
  v2f vpA = (v2f){0.f, 0.f}, vpB = (v2f){0.f, 0.f};

  for (int t = 0; t < LL - 1; ++t) {
    const int cn = toks[t + 1];
    // Early-issue all LDS for this body: row c_t (update), row c_{t+1} (dot),
    // next step's scalar k[lane] and k.k. Latency hides under divide+reduce.
    const float4* kvp = (const float4*)(T + c * H);
    const float4* knp = (const float4*)(T + cn * H);
    const float scn = T[cn * H + lane];
    const float kkn = KK[cn];

    const float vp = (vpA.x + vpA.y) + (vpB.x + vpB.y);
    const float dv = sc - vp / (kk + 1e-6f);  // true divide (matches reference)
    const float a = dv * (2.f * vp + dv * kk);
    const float s = wave_sum_dpp(a);          // wave-uniform
    const float dvg = s > 0.f ? dv : 0.f;     // branchless gate (fma(0,..)=id)
    wcount += s > 0.f ? 1.f : 0.f;
    const v2f dv2 = (v2f){dvg, dvg};

    v2f nA = (v2f){0.f, 0.f}, nB = (v2f){0.f, 0.f};
#pragma unroll
    for (int q = 0; q < 16; ++q) {
      const float4 kv4 = kvp[q];
      const float4 kn4 = knp[q];
      const v2f kva = (v2f){kv4.x, kv4.y}, kvb = (v2f){kv4.z, kv4.w};
      const v2f kna = (v2f){kn4.x, kn4.y}, knb = (v2f){kn4.z, kn4.w};
      M2[2 * q]     = __builtin_elementwise_fma(dv2, kva, M2[2 * q]);
      M2[2 * q + 1] = __builtin_elementwise_fma(dv2, kvb, M2[2 * q + 1]);
      nA = __builtin_elementwise_fma(M2[2 * q],     kna, nA);
      nB = __builtin_elementwise_fma(M2[2 * q + 1], knb, nB);
    }
    vpA = nA; vpB = nB;
    c = cn; sc = scn; kk = kkn;
  }

  // After the last iteration the fused dot already used row toks[LL-1]:
  // vp == ctx[lane] = M_final[lane] . k_last, in the same accumulation order.
  xv[lane] = (vpA.x + vpA.y) + (vpB.x + vpB.y);
  __syncthreads();
  float t1 = br[lane];
#pragma unroll 8
  for (int i = 0; i < H; ++i) t1 = fmaf(xv[i], Wr[i * H + lane], t1);
  __syncthreads();
  xv[lane] = t1;
  __syncthreads();
  float lg = bo[lane];
#pragma unroll 8
  for (int m = 0; m < H; ++m) lg = fmaf(xv[m], Wo[m * H + lane], lg);
  out[(long)b * H + lane] = lg;
  if (lane == 0) counts[b] = wcount;
}

__global__ __launch_bounds__(256, 1) void finalize_kernel(const float* __restrict__ counts,
                                                          float* __restrict__ out) {
  const int lane = threadIdx.x;  // 256 threads
  __shared__ float sbuf[BB];
  sbuf[lane] = counts[lane];
  __syncthreads();
  for (int off = BB / 2; off > 0; off >>= 1) {
    if (lane < off) sbuf[lane] += sbuf[lane + off];
    __syncthreads();
  }
  if (lane == 0) out[BB * H] = sbuf[0] / (float)(BB * (LL - 1));
}

extern "C" void kernel_launch(void* const* d_in, const int* in_sizes, int n_in,
                              void* d_out, int out_size, void* d_ws, size_t ws_size,
                              hipStream_t stream) {
  const int* seq      = (const int*)d_in[0];
  const float* embed  = (const float*)d_in[1];
  const float* W1     = (const float*)d_in[2];
  const float* b1     = (const float*)d_in[3];
  const float* W2     = (const float*)d_in[4];
  const float* b2     = (const float*)d_in[5];
  const float* gamma  = (const float*)d_in[6];
  const float* beta   = (const float*)d_in[7];
  const float* Wr     = (const float*)d_in[8];
  const float* br     = (const float*)d_in[9];
  const float* Wo     = (const float*)d_in[10];
  const float* bo     = (const float*)d_in[11];
  float* out = (float*)d_out;

  float* table  = (float*)d_ws;          // 64*64 f32
  float* kkg    = table + VOCAB * H;     // 64 f32
  float* counts = kkg + VOCAB;           // 256 f32

  encode_kernel<<<VOCAB, H, 0, stream>>>(embed, W1, b1, W2, b2, gamma, beta, table, kkg);
  scan_kernel<<<BB, H, 0, stream>>>(seq, table, kkg, Wr, br, Wo, bo, out, counts);
  finalize_kernel<<<1, BB, 0, stream>>>(counts, out);
}

// Round 4
// 676.823 us; speedup vs baseline: 2.3314x; 1.0710x over previous
//
#include <hip/hip_runtime.h>
#include <math.h>

#define VOCAB 64
#define H 64
#define BB 256
#define LL 2048

typedef float v2f __attribute__((ext_vector_type(2)));

// 64-lane wave sum via DPP (row_shr 1/2/4/8, row_bcast15, row_bcast31), then
// broadcast total from lane 63. All VALU-pipe, no LDS latency.
__device__ __forceinline__ float wave_sum_dpp(float x) {
  int t;
  float r = x;
  t = __builtin_amdgcn_update_dpp(0, __float_as_int(r), 0x111, 0xf, 0xf, true); r += __int_as_float(t);
  t = __builtin_amdgcn_update_dpp(0, __float_as_int(r), 0x112, 0xf, 0xf, true); r += __int_as_float(t);
  t = __builtin_amdgcn_update_dpp(0, __float_as_int(r), 0x114, 0xf, 0xf, true); r += __int_as_float(t);
  t = __builtin_amdgcn_update_dpp(0, __float_as_int(r), 0x118, 0xf, 0xf, true); r += __int_as_float(t);
  t = __builtin_amdgcn_update_dpp(0, __float_as_int(r), 0x142, 0xf, 0xf, true); r += __int_as_float(t);
  t = __builtin_amdgcn_update_dpp(0, __float_as_int(r), 0x143, 0xf, 0xf, true); r += __int_as_float(t);
  return __int_as_float(__builtin_amdgcn_readlane(__float_as_int(r), 63));
}

// Phase 1: hidden depends only on the token id -> precompute 64 hidden vectors.
__global__ __launch_bounds__(64, 1) void encode_kernel(
    const float* __restrict__ embed, const float* __restrict__ W1,
    const float* __restrict__ b1, const float* __restrict__ W2,
    const float* __restrict__ b2, const float* __restrict__ gamma,
    const float* __restrict__ beta, float* __restrict__ table,
    float* __restrict__ kkg) {
  const int c = blockIdx.x;
  const int j = threadIdx.x;
  __shared__ float hs[H];
  __shared__ float zs[2 * H];
  const float h = embed[c * H + j];
  hs[j] = h;
  __syncthreads();
  float z0 = b1[j], z1 = b1[j + H];
#pragma unroll 8
  for (int i = 0; i < H; ++i) {
    const float hi = hs[i];
    z0 = fmaf(hi, W1[i * 2 * H + j], z0);
    z1 = fmaf(hi, W1[i * 2 * H + j + H], z1);
  }
  z0 = fmaxf(z0, 0.f);
  z1 = fmaxf(z1, 0.f);
  zs[j] = z0;
  zs[j + H] = z1;
  __syncthreads();
  float ff = b2[j];
#pragma unroll 8
  for (int m = 0; m < 2 * H; ++m) ff = fmaf(zs[m], W2[m * H + j], ff);
  const float x = h + ff;
  const float mu = wave_sum_dpp(x) * (1.f / 64.f);
  const float d = x - mu;
  const float var = wave_sum_dpp(d * d) * (1.f / 64.f);
  const float y = d * (1.f / sqrtf(var + 1e-5f)) * gamma[j] + beta[j];
  table[c * H + j] = y;
  const float s2 = wave_sum_dpp(y * y);
  if (j == 0) kkg[c] = s2;
}

// One scan step. RU = row(c_t) (update), RD = row(c_{t+1}) (dot), RP gets
// row(c_{t+2}) prefetched for use one iteration later. Arithmetic order is
// bit-identical to the round-3 kernel; only load scheduling differs.
#define STEP(T_IDX, RU, RD, RP)                                              \
  {                                                                          \
    const int cp = cnn; /* c_{t+2}: prefetch its row+scalars now */          \
    const int tpre = ((T_IDX) + 3 < LL) ? (T_IDX) + 3 : LL - 1;              \
    const int cin = toks[tpre];                                              \
    const float scp = T[cp * H + lane];                                      \
    const float kkp = KK[cp];                                                \
    const float4* rp = (const float4*)(T + cp * H);                          \
    _Pragma("unroll")                                                        \
    for (int q = 0; q < 16; ++q) RP[q] = rp[q];                              \
    const float vp = (vpA.x + vpA.y) + (vpB.x + vpB.y);                      \
    const float dv = sc - vp / (kk + 1e-6f);                                 \
    const float aa = dv * (2.f * vp + dv * kk);                              \
    const float s = wave_sum_dpp(aa);                                        \
    const float dvg = s > 0.f ? dv : 0.f;                                    \
    wcount += s > 0.f ? 1.f : 0.f;                                           \
    const v2f dv2 = (v2f){dvg, dvg};                                         \
    v2f nA = (v2f){0.f, 0.f}, nB = (v2f){0.f, 0.f};                          \
    _Pragma("unroll")                                                        \
    for (int q = 0; q < 16; ++q) {                                           \
      const float4 kv4 = RU[q];                                              \
      const float4 kn4 = RD[q];                                              \
      const v2f kva = (v2f){kv4.x, kv4.y}, kvb = (v2f){kv4.z, kv4.w};        \
      const v2f kna = (v2f){kn4.x, kn4.y}, knb = (v2f){kn4.z, kn4.w};        \
      M2[2 * q]     = __builtin_elementwise_fma(dv2, kva, M2[2 * q]);        \
      M2[2 * q + 1] = __builtin_elementwise_fma(dv2, kvb, M2[2 * q + 1]);    \
      nA = __builtin_elementwise_fma(M2[2 * q],     kna, nA);                \
      nB = __builtin_elementwise_fma(M2[2 * q + 1], knb, nB);                \
    }                                                                        \
    vpA = nA; vpB = nB;                                                      \
    cn = cnn; cnn = cin;                                                     \
    sc = scn; kk = kkn; scn = scp; kkn = kkp;                                \
  }

// Phase 2+3: per-batch sequential scan. One block = one wave = one batch.
// Lane i owns row M[i][:]. Rows for steps t, t+1 are already in registers
// (3-buffer rotation, prefetched one iteration ahead) so no LDS latency sits
// on the recurrence critical path.
__global__ __launch_bounds__(64, 1) void scan_kernel(
    const int* __restrict__ seq, const float* __restrict__ table,
    const float* __restrict__ kkg, const float* __restrict__ Wr,
    const float* __restrict__ br, const float* __restrict__ Wo,
    const float* __restrict__ bo, float* __restrict__ out,
    float* __restrict__ counts) {
  const int b = blockIdx.x;
  const int lane = threadIdx.x;
  __shared__ float T[H * VOCAB];   // 16 KB: table, row c = key vector for token c
  __shared__ float KK[VOCAB];
  __shared__ int toks[LL];         // 8 KB: this batch's token stream
  __shared__ float xv[H];

  {
    const float4* src = (const float4*)table;
    float4* dst = (float4*)T;
#pragma unroll
    for (int q = 0; q < 16; ++q) dst[q * 64 + lane] = src[q * 64 + lane];
    KK[lane] = kkg[lane];
    const int4* ssrc = (const int4*)(seq + (long)b * LL);
    int4* sdst = (int4*)toks;
#pragma unroll
    for (int q = 0; q < 8; ++q) sdst[q * 64 + lane] = ssrc[q * 64 + lane];
  }
  __syncthreads();

  v2f M2[32];
#pragma unroll
  for (int r = 0; r < 32; ++r) M2[r] = (v2f){0.f, 0.f};
  float wcount = 0.f;

  // Pipeline prologue: rows/scalars for steps 0 and 1 in registers.
  float4 RA[16], RB[16], RC[16];
  const int c0 = toks[0];
  int cn = toks[1], cnn = toks[2];
  float sc = T[c0 * H + lane], kk = KK[c0];
  float scn = T[cn * H + lane], kkn = KK[cn];
  {
    const float4* r0 = (const float4*)(T + c0 * H);
    const float4* r1 = (const float4*)(T + cn * H);
#pragma unroll
    for (int q = 0; q < 16; ++q) { RA[q] = r0[q]; RB[q] = r1[q]; }
  }
  v2f vpA = (v2f){0.f, 0.f}, vpB = (v2f){0.f, 0.f};  // M=0 -> vp(0)=0

  int t = 0;
  for (int it = 0; it < 682; ++it) {   // 682*3 = 2046 steps
    STEP(t, RA, RB, RC); ++t;
    STEP(t, RB, RC, RA); ++t;
    STEP(t, RC, RA, RB); ++t;
  }
  STEP(t, RA, RB, RC);                 // t = 2046, last step; dot row = toks[2047]

  // The last fused dot used row toks[LL-1]: vp == ctx[lane] in the same
  // accumulation order as before.
  xv[lane] = (vpA.x + vpA.y) + (vpB.x + vpB.y);
  __syncthreads();
  float t1 = br[lane];
#pragma unroll 8
  for (int i = 0; i < H; ++i) t1 = fmaf(xv[i], Wr[i * H + lane], t1);
  __syncthreads();
  xv[lane] = t1;
  __syncthreads();
  float lg = bo[lane];
#pragma unroll 8
  for (int m = 0; m < H; ++m) lg = fmaf(xv[m], Wo[m * H + lane], lg);
  out[(long)b * H + lane] = lg;
  if (lane == 0) counts[b] = wcount;
}

__global__ __launch_bounds__(256, 1) void finalize_kernel(const float* __restrict__ counts,
                                                          float* __restrict__ out) {
  const int lane = threadIdx.x;  // 256 threads
  __shared__ float sbuf[BB];
  sbuf[lane] = counts[lane];
  __syncthreads();
  for (int off = BB / 2; off > 0; off >>= 1) {
    if (lane < off) sbuf[lane] += sbuf[lane + off];
    __syncthreads();
  }
  if (lane == 0) out[BB * H] = sbuf[0] / (float)(BB * (LL - 1));
}

extern "C" void kernel_launch(void* const* d_in, const int* in_sizes, int n_in,
                              void* d_out, int out_size, void* d_ws, size_t ws_size,
                              hipStream_t stream) {
  const int* seq      = (const int*)d_in[0];
  const float* embed  = (const float*)d_in[1];
  const float* W1     = (const float*)d_in[2];
  const float* b1     = (const float*)d_in[3];
  const float* W2     = (const float*)d_in[4];
  const float* b2     = (const float*)d_in[5];
  const float* gamma  = (const float*)d_in[6];
  const float* beta   = (const float*)d_in[7];
  const float* Wr     = (const float*)d_in[8];
  const float* br     = (const float*)d_in[9];
  const float* Wo     = (const float*)d_in[10];
  const float* bo     = (const float*)d_in[11];
  float* out = (float*)d_out;

  float* table  = (float*)d_ws;          // 64*64 f32
  float* kkg    = table + VOCAB * H;     // 64 f32
  float* counts = kkg + VOCAB;           // 256 f32

  encode_kernel<<<VOCAB, H, 0, stream>>>(embed, W1, b1, W2, b2, gamma, beta, table, kkg);
  scan_kernel<<<BB, H, 0, stream>>>(seq, table, kkg, Wr, br, Wo, bo, out, counts);
  finalize_kernel<<<1, BB, 0, stream>>>(counts, out);
}

// Round 5
// 665.507 us; speedup vs baseline: 2.3711x; 1.0170x over previous
//
#include <hip/hip_runtime.h>
#include <math.h>

#define VOCAB 64
#define H 64
#define BB 256
#define LL 2048

typedef float v2f __attribute__((ext_vector_type(2)));

// Force a value to be materialized in a VGPR at this point (defeats the
// compiler's load-folding of "prefetch" copies back into their use sites).
#define PIN(x)  asm volatile("" : "+v"(x))
#define PIN4(f) asm volatile("" : "+v"(f.x), "+v"(f.y), "+v"(f.z), "+v"(f.w))

// 64-lane wave sum via DPP (row_shr 1/2/4/8, row_bcast15, row_bcast31), then
// broadcast total from lane 63. All VALU-pipe, no LDS latency.
__device__ __forceinline__ float wave_sum_dpp(float x) {
  int t;
  float r = x;
  t = __builtin_amdgcn_update_dpp(0, __float_as_int(r), 0x111, 0xf, 0xf, true); r += __int_as_float(t);
  t = __builtin_amdgcn_update_dpp(0, __float_as_int(r), 0x112, 0xf, 0xf, true); r += __int_as_float(t);
  t = __builtin_amdgcn_update_dpp(0, __float_as_int(r), 0x114, 0xf, 0xf, true); r += __int_as_float(t);
  t = __builtin_amdgcn_update_dpp(0, __float_as_int(r), 0x118, 0xf, 0xf, true); r += __int_as_float(t);
  t = __builtin_amdgcn_update_dpp(0, __float_as_int(r), 0x142, 0xf, 0xf, true); r += __int_as_float(t);
  t = __builtin_amdgcn_update_dpp(0, __float_as_int(r), 0x143, 0xf, 0xf, true); r += __int_as_float(t);
  return __int_as_float(__builtin_amdgcn_readlane(__float_as_int(r), 63));
}

// Phase 1: hidden depends only on the token id -> precompute 64 hidden vectors.
__global__ __launch_bounds__(64, 1) void encode_kernel(
    const float* __restrict__ embed, const float* __restrict__ W1,
    const float* __restrict__ b1, const float* __restrict__ W2,
    const float* __restrict__ b2, const float* __restrict__ gamma,
    const float* __restrict__ beta, float* __restrict__ table,
    float* __restrict__ kkg) {
  const int c = blockIdx.x;
  const int j = threadIdx.x;
  __shared__ float hs[H];
  __shared__ float zs[2 * H];
  const float h = embed[c * H + j];
  hs[j] = h;
  __syncthreads();
  float z0 = b1[j], z1 = b1[j + H];
#pragma unroll 8
  for (int i = 0; i < H; ++i) {
    const float hi = hs[i];
    z0 = fmaf(hi, W1[i * 2 * H + j], z0);
    z1 = fmaf(hi, W1[i * 2 * H + j + H], z1);
  }
  z0 = fmaxf(z0, 0.f);
  z1 = fmaxf(z1, 0.f);
  zs[j] = z0;
  zs[j + H] = z1;
  __syncthreads();
  float ff = b2[j];
#pragma unroll 8
  for (int m = 0; m < 2 * H; ++m) ff = fmaf(zs[m], W2[m * H + j], ff);
  const float x = h + ff;
  const float mu = wave_sum_dpp(x) * (1.f / 64.f);
  const float d = x - mu;
  const float var = wave_sum_dpp(d * d) * (1.f / 64.f);
  const float y = d * (1.f / sqrtf(var + 1e-5f)) * gamma[j] + beta[j];
  table[c * H + j] = y;
  const float s2 = wave_sum_dpp(y * y);
  if (j == 0) kkg[c] = s2;
}

// One scan step. RU = row(c_t) (update), RD = row(c_{t+1}) (dot), RP gets
// row(c_{t+2}) prefetched for use one iteration later. Arithmetic order is
// bit-identical to rounds 2-4; only load scheduling differs. The PINs at the
// bottom force RP + next-next scalars into VGPRs *after* this step's compute,
// so the LDS latency of the prefetch never touches the recurrence chain.
#define STEP(T_IDX, RU, RD, RP)                                              \
  {                                                                          \
    const int cp = cnn; /* c_{t+2}: prefetch its row+scalars now */          \
    const int tpre = ((T_IDX) + 3 < LL) ? (T_IDX) + 3 : LL - 1;              \
    int cin = toks[tpre];                                                    \
    float scp = T[cp * H + lane];                                            \
    float kkp = KK[cp];                                                      \
    const float4* rp = (const float4*)(T + cp * H);                          \
    _Pragma("unroll")                                                        \
    for (int q = 0; q < 16; ++q) RP[q] = rp[q];                              \
    const float vp = (vpA.x + vpA.y) + (vpB.x + vpB.y);                      \
    const float dv = sc - vp / (kk + 1e-6f);                                 \
    const float aa = dv * (2.f * vp + dv * kk);                              \
    const float s = wave_sum_dpp(aa);                                        \
    const float dvg = s > 0.f ? dv : 0.f;                                    \
    wcount += s > 0.f ? 1.f : 0.f;                                           \
    const v2f dv2 = (v2f){dvg, dvg};                                         \
    v2f nA = (v2f){0.f, 0.f}, nB = (v2f){0.f, 0.f};                          \
    _Pragma("unroll")                                                        \
    for (int q = 0; q < 16; ++q) {                                           \
      const float4 kv4 = RU[q];                                              \
      const float4 kn4 = RD[q];                                              \
      const v2f kva = (v2f){kv4.x, kv4.y}, kvb = (v2f){kv4.z, kv4.w};        \
      const v2f kna = (v2f){kn4.x, kn4.y}, knb = (v2f){kn4.z, kn4.w};        \
      M2[2 * q]     = __builtin_elementwise_fma(dv2, kva, M2[2 * q]);        \
      M2[2 * q + 1] = __builtin_elementwise_fma(dv2, kvb, M2[2 * q + 1]);    \
      nA = __builtin_elementwise_fma(M2[2 * q],     kna, nA);                \
      nB = __builtin_elementwise_fma(M2[2 * q + 1], knb, nB);                \
    }                                                                        \
    vpA = nA; vpB = nB;                                                      \
    _Pragma("unroll")                                                        \
    for (int q = 0; q < 16; ++q) PIN4(RP[q]);                                \
    PIN(scp); PIN(kkp); PIN(cin);                                            \
    cn = cnn; cnn = cin;                                                     \
    sc = scn; kk = kkn; scn = scp; kkn = kkp;                                \
  }

// Phase 2+3: per-batch sequential scan. One block = one wave = one batch.
// Lane i owns row M[i][:]. Rows for steps t, t+1 are pinned in registers
// (3-buffer rotation, prefetched one iteration ahead) so no LDS latency sits
// on the recurrence critical path.
__global__ __launch_bounds__(64, 1) void scan_kernel(
    const int* __restrict__ seq, const float* __restrict__ table,
    const float* __restrict__ kkg, const float* __restrict__ Wr,
    const float* __restrict__ br, const float* __restrict__ Wo,
    const float* __restrict__ bo, float* __restrict__ out,
    float* __restrict__ counts) {
  const int b = blockIdx.x;
  const int lane = threadIdx.x;
  __shared__ float T[H * VOCAB];   // 16 KB: table, row c = key vector for token c
  __shared__ float KK[VOCAB];
  __shared__ int toks[LL];         // 8 KB: this batch's token stream
  __shared__ float xv[H];

  {
    const float4* src = (const float4*)table;
    float4* dst = (float4*)T;
#pragma unroll
    for (int q = 0; q < 16; ++q) dst[q * 64 + lane] = src[q * 64 + lane];
    KK[lane] = kkg[lane];
    const int4* ssrc = (const int4*)(seq + (long)b * LL);
    int4* sdst = (int4*)toks;
#pragma unroll
    for (int q = 0; q < 8; ++q) sdst[q * 64 + lane] = ssrc[q * 64 + lane];
  }
  __syncthreads();

  v2f M2[32];
#pragma unroll
  for (int r = 0; r < 32; ++r) M2[r] = (v2f){0.f, 0.f};
  float wcount = 0.f;

  // Pipeline prologue: rows/scalars for steps 0 and 1 in registers.
  float4 RA[16], RB[16], RC[16];
  const int c0 = toks[0];
  int cn = toks[1], cnn = toks[2];
  float sc = T[c0 * H + lane], kk = KK[c0];
  float scn = T[cn * H + lane], kkn = KK[cn];
  {
    const float4* r0 = (const float4*)(T + c0 * H);
    const float4* r1 = (const float4*)(T + cn * H);
#pragma unroll
    for (int q = 0; q < 16; ++q) { RA[q] = r0[q]; RB[q] = r1[q]; }
#pragma unroll
    for (int q = 0; q < 16; ++q) { PIN4(RA[q]); PIN4(RB[q]); }
  }
  v2f vpA = (v2f){0.f, 0.f}, vpB = (v2f){0.f, 0.f};  // M=0 -> vp(0)=0

  int t = 0;
  for (int it = 0; it < 682; ++it) {   // 682*3 = 2046 steps
    STEP(t, RA, RB, RC); ++t;
    STEP(t, RB, RC, RA); ++t;
    STEP(t, RC, RA, RB); ++t;
  }
  STEP(t, RA, RB, RC);                 // t = 2046, last step; dot row = toks[2047]

  // The last fused dot used row toks[LL-1]: vp == ctx[lane] in the same
  // accumulation order as before.
  xv[lane] = (vpA.x + vpA.y) + (vpB.x + vpB.y);
  __syncthreads();
  float t1 = br[lane];
#pragma unroll 8
  for (int i = 0; i < H; ++i) t1 = fmaf(xv[i], Wr[i * H + lane], t1);
  __syncthreads();
  xv[lane] = t1;
  __syncthreads();
  float lg = bo[lane];
#pragma unroll 8
  for (int m = 0; m < H; ++m) lg = fmaf(xv[m], Wo[m * H + lane], lg);
  out[(long)b * H + lane] = lg;
  if (lane == 0) counts[b] = wcount;
}

__global__ __launch_bounds__(256, 1) void finalize_kernel(const float* __restrict__ counts,
                                                          float* __restrict__ out) {
  const int lane = threadIdx.x;  // 256 threads
  __shared__ float sbuf[BB];
  sbuf[lane] = counts[lane];
  __syncthreads();
  for (int off = BB / 2; off > 0; off >>= 1) {
    if (lane < off) sbuf[lane] += sbuf[lane + off];
    __syncthreads();
  }
  if (lane == 0) out[BB * H] = sbuf[0] / (float)(BB * (LL - 1));
}

extern "C" void kernel_launch(void* const* d_in, const int* in_sizes, int n_in,
                              void* d_out, int out_size, void* d_ws, size_t ws_size,
                              hipStream_t stream) {
  const int* seq      = (const int*)d_in[0];
  const float* embed  = (const float*)d_in[1];
  const float* W1     = (const float*)d_in[2];
  const float* b1     = (const float*)d_in[3];
  const float* W2     = (const float*)d_in[4];
  const float* b2     = (const float*)d_in[5];
  const float* gamma  = (const float*)d_in[6];
  const float* beta   = (const float*)d_in[7];
  const float* Wr     = (const float*)d_in[8];
  const float* br     = (const float*)d_in[9];
  const float* Wo     = (const float*)d_in[10];
  const float* bo     = (const float*)d_in[11];
  float* out = (float*)d_out;

  float* table  = (float*)d_ws;          // 64*64 f32
  float* kkg    = table + VOCAB * H;     // 64 f32
  float* counts = kkg + VOCAB;           // 256 f32

  encode_kernel<<<VOCAB, H, 0, stream>>>(embed, W1, b1, W2, b2, gamma, beta, table, kkg);
  scan_kernel<<<BB, H, 0, stream>>>(seq, table, kkg, Wr, br, Wo, bo, out, counts);
  finalize_kernel<<<1, BB, 0, stream>>>(counts, out);
}